// Round 4
// baseline (415.811 us; speedup 1.0000x reference)
//
#include <hip/hip_runtime.h>
#include <hip/hip_bf16.h>
#include <hip/hip_cooperative_groups.h>

namespace cg = cooperative_groups;

// All tensors are float32 (verified: runtime dtype probe took the f32 branch).
//
// R3 post-mortem: attn fixed (es4 b128 + global x + precomputed mask bits);
// top-5 is now all k_rnn (~45 us, established floor) + harness fill (~41).
// Residual is launch gaps across 4 kernels. R4: single cooperative launch,
// 2 grid syncs; attn restructured to (b,q)-unit x 4 heads with fused
// out/xw epilogue (same per-thread cost as R3's measured attn, same FMA
// order -> identical numerics). Fallback to the R3 4-kernel pipeline if
// cooperative launch is rejected.

#define NB 16
#define NL 256
#define NLQ 64
#define NDIN 32
#define NET 128
#define NH 4
#define NETK 32

// Padded LDS layout for h/tmp in rnn (conflicts verified 0).
#define HPAD 136
#define PAD(i) ((i) + 4 * ((i) >> 6))

// ---------------------------------------------------------------------------
// shared helpers
// ---------------------------------------------------------------------------
__device__ __forceinline__ void layer128(const float* src_lds,
                                         const float* __restrict__ W,
                                         const float* __restrict__ bvec,
                                         float* dst_lds, int j, int s) {
  const float4* h4 = (const float4*)(src_lds + s * 68);
  float a0 = 0.f, a1 = 0.f, a2 = 0.f, a3 = 0.f;
#pragma unroll
  for (int i = 0; i < 16; i++) {
    float4 hv = h4[i];
    int base = (s * 64 + 4 * i) * NET + j;
    a0 += hv.x * W[base];
    a1 += hv.y * W[base + NET];
    a2 += hv.z * W[base + 2 * NET];
    a3 += hv.w * W[base + 3 * NET];
  }
  float acc = (a0 + a1) + (a2 + a3);
  acc += __shfl_xor(acc, 1, 64);
  if (s == 0) dst_lds[PAD(j)] = acc + bvec[j];
}

// one embed+proj unit (8 rows) with 256 threads: half = t>>7 owns 4 rows.
__device__ __forceinline__ void embed_unit256(
    float* emb, const float* __restrict__ tsrc, int base,
    float wl, float bl, float wp, float bp,
    const float* __restrict__ W, float bias,
    float* __restrict__ dst, int t) {
  int j = t & 127, half = t >> 7;
  __syncthreads();  // guard emb reuse across units
#pragma unroll
  for (int rr = 0; rr < 4; rr++) {
    int r = half * 4 + rr;
    float tv = tsrc[base + r];
    emb[r * NET + j] = (j == 0) ? (tv * wl + bl) : sinf(tv * wp + bp);
  }
  __syncthreads();
  float acc[4] = {bias, bias, bias, bias};
#pragma unroll 2
  for (int i = 0; i < NET; i += 4) {
    float w0 = W[(size_t)i * NET + j];
    float w1 = W[(size_t)(i + 1) * NET + j];
    float w2 = W[(size_t)(i + 2) * NET + j];
    float w3 = W[(size_t)(i + 3) * NET + j];
#pragma unroll
    for (int rr = 0; rr < 4; rr++) {
      float4 e4 = *(const float4*)&emb[(half * 4 + rr) * NET + i];
      acc[rr] += e4.x * w0 + e4.y * w1 + e4.z * w2 + e4.w * w3;
    }
  }
#pragma unroll
  for (int rr = 0; rr < 4; rr++)
    dst[(size_t)(base + half * 4 + rr) * NET + j] = acc[rr];
}

// ---------------------------------------------------------------------------
// Mega-kernel: 3 phases, 2 grid syncs. 256 threads, <=1024 blocks (strided
// work loops tolerate any co-resident grid size).
// ---------------------------------------------------------------------------
__global__ __launch_bounds__(256, 4) void k_mega(
    const float* __restrict__ x, const float* __restrict__ ts,
    const float* __restrict__ mask, const float* __restrict__ query,
    const float* __restrict__ w_lin, const float* __restrict__ b_lin,
    const float* __restrict__ w_per, const float* __restrict__ b_per,
    const float* __restrict__ Wq, const float* __restrict__ bq,
    const float* __restrict__ Wk, const float* __restrict__ bk,
    const float* __restrict__ Wo, const float* __restrict__ bo,
    const float* __restrict__ Wih, const float* __restrict__ bih,
    const float* __restrict__ Whh, const float* __restrict__ bhh,
    const float* __restrict__ r1w, const float* __restrict__ r1b,
    const float* __restrict__ r2w, const float* __restrict__ r2b,
    const float* __restrict__ r3w, const float* __restrict__ r3b,
    const float* __restrict__ r4w, const float* __restrict__ r4b,
    float* __restrict__ kproj, float* __restrict__ qproj,
    float* __restrict__ XW, unsigned* __restrict__ mbg,
    float* __restrict__ out) {
  __shared__ __align__(16) float lds[8704];  // 34 KB, aliased per phase
  cg::grid_group grid = cg::this_grid();
  int blk = blockIdx.x;
  int nblk = gridDim.x;
  int t = threadIdx.x;

  // ---- phase 1: embed+proj (520 units) + mask pack (16 units) ----
  {
    int j = t & 127;
    float wl = w_lin[0], bl = b_lin[0];
    float wp = (j > 0) ? w_per[j - 1] : 0.f;
    float bp = (j > 0) ? b_per[j - 1] : 0.f;
    for (int u = blk; u < 536; u += nblk) {
      if (u < 512) {
        embed_unit256(lds, ts, u * 8, wl, bl, wp, bp, Wk, bk[j], kproj, t);
      } else if (u < 520) {
        embed_unit256(lds, query, (u - 512) * 8, wl, bl, wp, bp, Wq, bq[j],
                      qproj, t);
      } else {
        int b = u - 520;
        const float4* mr4 =
            (const float4*)(mask + (size_t)(b * NL + t) * NDIN);
        unsigned bits = 0;
#pragma unroll
        for (int v = 0; v < 8; v++) {
          float4 m = mr4[v];
          bits |= (m.x != 0.f ? 1u : 0u) << (4 * v);
          bits |= (m.y != 0.f ? 1u : 0u) << (4 * v + 1);
          bits |= (m.z != 0.f ? 1u : 0u) << (4 * v + 2);
          bits |= (m.w != 0.f ? 1u : 0u) << (4 * v + 3);
        }
        mbg[b * NL + t] = bits;
      }
    }
  }
  grid.sync();

  // ---- phase 2: attention (all heads) + out/xw epilogue. unit = (b,q). ----
  {
    const float SC = 0.17677669529663687f;  // 1/sqrt(32)
    float* es   = lds;         // 256*4 = 1024: [k][h]
    float* part = lds + 1024;  // 3*32*9 = 864
    float* arow = lds + 1920;  // 256
    float* orow = lds + 2176;  // 128
    for (int u = blk; u < NB * NLQ; u += nblk) {
      __syncthreads();  // prev iteration's LDS reads complete
      int b = u >> 6, q = u & 63;
      // A: thread t = key row k; 4 head scores -> one float4 write.
      {
        int k = t;
        const float* kpr = kproj + (size_t)(b * NL + k) * NET;
        float ev[NH];
#pragma unroll
        for (int h = 0; h < NH; h++) {
          float kr[NETK];
          const float4* kp = (const float4*)(kpr + h * NETK);
#pragma unroll
          for (int i = 0; i < 8; i++) {
            float4 v = kp[i];
            kr[4 * i] = v.x; kr[4 * i + 1] = v.y;
            kr[4 * i + 2] = v.z; kr[4 * i + 3] = v.w;
          }
          // block-uniform address -> scalar loads
          const float* qv = qproj + (size_t)q * NET + h * NETK;
          float s0 = 0.f, s1 = 0.f;
#pragma unroll
          for (int i = 0; i < NETK; i += 2) {
            s0 += qv[i] * kr[i];
            s1 += qv[i + 1] * kr[i + 1];
          }
          ev[h] = __expf((s0 + s1) * SC);
        }
        *(float4*)&es[k * 4] = make_float4(ev[0], ev[1], ev[2], ev[3]);
      }
      __syncthreads();
      // B: thread = (kq = t>>5, c = t&31), 32 k-iters each.
      float den[NH] = {0.f, 0.f, 0.f, 0.f};
      float num[NH] = {0.f, 0.f, 0.f, 0.f};
      float sumx = 0.f;
      int c = t & 31;
      {
        int kq = t >> 5;
        const float* xb = x + (size_t)b * NL * NDIN;
        const unsigned* mbb = mbg + b * NL;
        int k0 = kq * 32;
#pragma unroll 4
        for (int kk = 0; kk < 32; kk++) {
          int k = k0 + kk;
          float4 e4 = *(const float4*)&es[k * 4];
          float xv = xb[(size_t)k * NDIN + c];
          float mv = ((mbb[k] >> c) & 1u) ? 1.f : 0.f;
          sumx += xv;
          float e0 = e4.x * mv, e1 = e4.y * mv, e2 = e4.z * mv, e3 = e4.w * mv;
          den[0] += e0; num[0] += e0 * xv;
          den[1] += e1; num[1] += e1 * xv;
          den[2] += e2; num[2] += e2 * xv;
          den[3] += e3; num[3] += e3 * xv;
        }
      }
      sumx += __shfl_xor(sumx, 32, 64);
#pragma unroll
      for (int hh = 0; hh < NH; hh++) {
        den[hh] += __shfl_xor(den[hh], 32, 64);
        num[hh] += __shfl_xor(num[hh], 32, 64);
      }
      {
        int w = t >> 6, l = t & 63;
        if (w > 0 && l < 32) {
          float* p = &part[((w - 1) * 32 + c) * 9];  // stride 9: conflict-free
#pragma unroll
          for (int hh = 0; hh < NH; hh++) { p[hh] = den[hh]; p[4 + hh] = num[hh]; }
          p[8] = sumx;
        }
      }
      __syncthreads();
      if (t < 32) {
#pragma unroll
        for (int ww = 0; ww < 3; ww++) {
          const float* p = &part[(ww * 32 + t) * 9];
#pragma unroll
          for (int hh = 0; hh < NH; hh++) { den[hh] += p[hh]; num[hh] += p[4 + hh]; }
          sumx += p[8];
        }
        float meanx = sumx * (1.f / 256.f);
#pragma unroll
        for (int hh = 0; hh < NH; hh++) {
          bool any = (den[hh] > 0.f);
          arow[hh * 64 + t]      = any ? (num[hh] / den[hh]) : meanx;
          arow[hh * 64 + 32 + t] = any ? 1.f : 0.f;
        }
      }
      __syncthreads();
      // epilogue 1: orow[j] = arow . Wo[:,j] + bo[j]
      if (t < 128) {
        float o0 = bo[t], o1 = 0.f, o2 = 0.f, o3 = 0.f;
#pragma unroll 4
        for (int uu = 0; uu < 256; uu += 4) {
          float4 av = *(const float4*)&arow[uu];
          o0 += av.x * Wo[(size_t)uu * NET + t];
          o1 += av.y * Wo[(size_t)(uu + 1) * NET + t];
          o2 += av.z * Wo[(size_t)(uu + 2) * NET + t];
          o3 += av.w * Wo[(size_t)(uu + 3) * NET + t];
        }
        orow[t] = (o0 + o1) + (o2 + o3);
      }
      __syncthreads();
      // epilogue 2: XW[q][j] = orow . Wih[:,j] + bih[j] + bhh[j]
      if (t < 128) {
        float a0 = bih[t] + bhh[t], a1 = 0.f, a2 = 0.f, a3 = 0.f;
#pragma unroll 4
        for (int e = 0; e < NET; e += 4) {
          float4 ov = *(const float4*)&orow[e];
          a0 += ov.x * Wih[(size_t)e * NET + t];
          a1 += ov.y * Wih[(size_t)(e + 1) * NET + t];
          a2 += ov.z * Wih[(size_t)(e + 2) * NET + t];
          a3 += ov.w * Wih[(size_t)(e + 3) * NET + t];
        }
        XW[(size_t)(b * NLQ + q) * NET + t] = (a0 + a1) + (a2 + a3);
      }
    }
  }
  grid.sync();

  // ---- phase 3: sequential RNN + regressor (16 units) ----
  for (int b = blk; b < NB; b += nblk) {
    float* xwl = lds;                       // 8192
    float* hb0 = lds + 8192;                // HPAD
    float* hb1 = lds + 8192 + HPAD;         // HPAD
    float* tmp = lds + 8192 + 2 * HPAD;     // HPAD
    int s = t & 1, j = t >> 1;
    {
      const float4* src = (const float4*)(XW + (size_t)b * NLQ * NET);
      float4* dst = (float4*)xwl;
#pragma unroll
      for (int v = 0; v < 8; v++) dst[t + 256 * v] = src[t + 256 * v];
    }
    float w[64];
#pragma unroll
    for (int i = 0; i < 64; i++) w[i] = Whh[(s * 64 + i) * NET + j];
    if (t < 128) hb0[PAD(t)] = 0.f;
    __syncthreads();
    for (int tt = 0; tt < NLQ; tt++) {
      float xwv = xwl[tt * NET + j];
      const float* hsrc = (tt & 1) ? hb1 : hb0;
      const float4* h4 = (const float4*)&hsrc[s * 68];
      float a0 = 0.f, a1 = 0.f, a2 = 0.f, a3 = 0.f;
#pragma unroll
      for (int i = 0; i < 16; i++) {
        float4 hv = h4[i];
        a0 += hv.x * w[4 * i];
        a1 += hv.y * w[4 * i + 1];
        a2 += hv.z * w[4 * i + 2];
        a3 += hv.w * w[4 * i + 3];
      }
      float acc = (a0 + a1) + (a2 + a3);
      acc += __shfl_xor(acc, 1, 64);
      if (s == 0) {
        float z = acc + xwv;
        float e2 = __expf(2.f * z);
        float* hdst = (tt & 1) ? hb0 : hb1;
        hdst[PAD(j)] = 1.f - 2.f / (e2 + 1.f);  // tanh(z)
      }
      __syncthreads();
    }
    layer128(hb0, r1w, r1b, tmp, j, s);
    __syncthreads();
    layer128(tmp, r2w, r2b, hb1, j, s);
    __syncthreads();
    layer128(hb1, r3w, r3b, hb0, j, s);
    __syncthreads();
    if (t < 64) {
      int jj = t >> 3, p = t & 7;
      float y = 0.f;
#pragma unroll
      for (int i = 0; i < 16; i++) {
        int ii = p * 16 + i;
        y += hb0[PAD(ii)] * r4w[ii * 8 + jj];
      }
      y += __shfl_xor(y, 1, 64);
      y += __shfl_xor(y, 2, 64);
      y += __shfl_xor(y, 4, 64);
      if (p == 0) out[b * 8 + jj] = y + r4b[jj];
    }
  }
}

// ===========================================================================
// Fallback path: R3's verified 4-kernel pipeline (used only if cooperative
// launch is rejected by the runtime/capture).
// ===========================================================================
__global__ __launch_bounds__(128) void k_embed_proj(
    const float* __restrict__ ts, const float* __restrict__ query,
    const float* __restrict__ mask,
    const float* __restrict__ w_lin, const float* __restrict__ b_lin,
    const float* __restrict__ w_per, const float* __restrict__ b_per,
    const float* __restrict__ Wk, const float* __restrict__ bk,
    const float* __restrict__ Wq, const float* __restrict__ bq,
    float* __restrict__ kproj, float* __restrict__ qproj,
    unsigned* __restrict__ mbg) {
  __shared__ __align__(16) float emb[8 * NET];
  int g = blockIdx.x;
  int j = threadIdx.x;
  if (g >= 520) {
    int b = g - 520;
#pragma unroll
    for (int half = 0; half < 2; half++) {
      int r = j + 128 * half;
      const float4* mr4 = (const float4*)(mask + (size_t)(b * NL + r) * NDIN);
      unsigned bits = 0;
#pragma unroll
      for (int u = 0; u < 8; u++) {
        float4 m = mr4[u];
        bits |= (m.x != 0.f ? 1u : 0u) << (4 * u);
        bits |= (m.y != 0.f ? 1u : 0u) << (4 * u + 1);
        bits |= (m.z != 0.f ? 1u : 0u) << (4 * u + 2);
        bits |= (m.w != 0.f ? 1u : 0u) << (4 * u + 3);
      }
      mbg[b * NL + r] = bits;
    }
    return;
  }
  bool isQ = (g >= 512);
  int base = (isQ ? g - 512 : g) * 8;
  float wl_ = w_lin[0], bl_ = b_lin[0];
  float wp = (j > 0) ? w_per[j - 1] : 0.f;
  float bp = (j > 0) ? b_per[j - 1] : 0.f;
#pragma unroll
  for (int rr = 0; rr < 8; rr++) {
    float t = isQ ? query[base + rr] : ts[base + rr];
    emb[rr * NET + j] = (j == 0) ? (t * wl_ + bl_) : sinf(t * wp + bp);
  }
  __syncthreads();
  const float* W = isQ ? Wq : Wk;
  float bias = isQ ? bq[j] : bk[j];
  float acc[8];
#pragma unroll
  for (int rr = 0; rr < 8; rr++) acc[rr] = bias;
#pragma unroll 2
  for (int i = 0; i < NET; i += 4) {
    float w0 = W[(size_t)i * NET + j];
    float w1 = W[(size_t)(i + 1) * NET + j];
    float w2 = W[(size_t)(i + 2) * NET + j];
    float w3 = W[(size_t)(i + 3) * NET + j];
#pragma unroll
    for (int rr = 0; rr < 8; rr++) {
      float4 e4 = *(const float4*)&emb[rr * NET + i];
      acc[rr] += e4.x * w0 + e4.y * w1 + e4.z * w2 + e4.w * w3;
    }
  }
  float* dst = isQ ? qproj : kproj;
#pragma unroll
  for (int rr = 0; rr < 8; rr++) dst[(size_t)(base + rr) * NET + j] = acc[rr];
}

__global__ __launch_bounds__(256) void k_attn(
    const float* __restrict__ x, const unsigned* __restrict__ mbg,
    const float* __restrict__ qproj, const float* __restrict__ kproj,
    float* __restrict__ att) {
  const float SC = 0.17677669529663687f;
  int blk = blockIdx.x;
  int qg = blk & 15;
  int h  = (blk >> 4) & 3;
  int b  = blk >> 6;
  int t  = threadIdx.x;
  __shared__ __align__(16) float es4[NL * 4];
  __shared__ float part[3 * 32 * 9];
  {
    int k = t;
    float kr[NETK];
    const float4* kp =
        (const float4*)(kproj + (size_t)(b * NL + k) * NET + h * NETK);
#pragma unroll
    for (int i = 0; i < 8; i++) {
      float4 v = kp[i];
      kr[4 * i] = v.x; kr[4 * i + 1] = v.y;
      kr[4 * i + 2] = v.z; kr[4 * i + 3] = v.w;
    }
    float ev[4];
#pragma unroll
    for (int qq = 0; qq < 4; qq++) {
      const float* qv = qproj + (size_t)(qg * 4 + qq) * NET + h * NETK;
      float s0 = 0.f, s1 = 0.f;
#pragma unroll
      for (int i = 0; i < NETK; i += 2) {
        s0 += qv[i] * kr[i];
        s1 += qv[i + 1] * kr[i + 1];
      }
      ev[qq] = __expf((s0 + s1) * SC);
    }
    *(float4*)&es4[k * 4] = make_float4(ev[0], ev[1], ev[2], ev[3]);
  }
  __syncthreads();
  int kq = t >> 5, c = t & 31;
  float den[4] = {0.f, 0.f, 0.f, 0.f};
  float num[4] = {0.f, 0.f, 0.f, 0.f};
  float sumx = 0.f;
  {
    const float* xb = x + (size_t)b * NL * NDIN;
    const unsigned* mbb = mbg + b * NL;
    int k0 = kq * 32;
#pragma unroll 4
    for (int kk = 0; kk < 32; kk++) {
      int k = k0 + kk;
      float4 e4 = *(const float4*)&es4[k * 4];
      float xv = xb[(size_t)k * NDIN + c];
      float mv = ((mbb[k] >> c) & 1u) ? 1.f : 0.f;
      sumx += xv;
      float e0 = e4.x * mv, e1 = e4.y * mv, e2 = e4.z * mv, e3 = e4.w * mv;
      den[0] += e0; num[0] += e0 * xv;
      den[1] += e1; num[1] += e1 * xv;
      den[2] += e2; num[2] += e2 * xv;
      den[3] += e3; num[3] += e3 * xv;
    }
  }
  sumx += __shfl_xor(sumx, 32, 64);
#pragma unroll
  for (int q = 0; q < 4; q++) {
    den[q] += __shfl_xor(den[q], 32, 64);
    num[q] += __shfl_xor(num[q], 32, 64);
  }
  {
    int w = t >> 6, lane = t & 63;
    if (w > 0 && lane < 32) {
      float* p = &part[((w - 1) * 32 + c) * 9];
#pragma unroll
      for (int q = 0; q < 4; q++) { p[q] = den[q]; p[4 + q] = num[q]; }
      p[8] = sumx;
    }
  }
  __syncthreads();
  if (t < 32) {
#pragma unroll
    for (int ww = 0; ww < 3; ww++) {
      const float* p = &part[(ww * 32 + t) * 9];
#pragma unroll
      for (int q = 0; q < 4; q++) { den[q] += p[q]; num[q] += p[4 + q]; }
      sumx += p[8];
    }
    float meanx = sumx * (1.f / 256.f);
#pragma unroll
    for (int qq = 0; qq < 4; qq++) {
      bool any = (den[qq] > 0.f);
      float* ao = att + (size_t)(((b * NLQ + qg * 4 + qq) * NH) + h) * 64;
      ao[t]      = any ? (num[qq] / den[qq]) : meanx;
      ao[32 + t] = any ? 1.f : 0.f;
    }
  }
}

__global__ __launch_bounds__(128) void k_out_xw(
    const float* __restrict__ att,
    const float* __restrict__ Wo, const float* __restrict__ bo,
    const float* __restrict__ Wih, const float* __restrict__ bih,
    const float* __restrict__ bhh, float* __restrict__ XW) {
  int r = blockIdx.x;
  int j = threadIdx.x;
  __shared__ __align__(16) float arow[NH * 64];
  __shared__ __align__(16) float orow[NET];
  arow[j]       = att[(size_t)r * 256 + j];
  arow[j + 128] = att[(size_t)r * 256 + 128 + j];
  __syncthreads();
  float a0 = bo[j], a1 = 0.f, a2 = 0.f, a3 = 0.f;
#pragma unroll 4
  for (int u = 0; u < 256; u += 4) {
    float4 av = *(const float4*)&arow[u];
    a0 += av.x * Wo[(size_t)u * NET + j];
    a1 += av.y * Wo[(size_t)(u + 1) * NET + j];
    a2 += av.z * Wo[(size_t)(u + 2) * NET + j];
    a3 += av.w * Wo[(size_t)(u + 3) * NET + j];
  }
  orow[j] = (a0 + a1) + (a2 + a3);
  __syncthreads();
  float b0 = bih[j] + bhh[j], b1 = 0.f, b2 = 0.f, b3 = 0.f;
#pragma unroll 4
  for (int e = 0; e < NET; e += 4) {
    float4 ov = *(const float4*)&orow[e];
    b0 += ov.x * Wih[(size_t)e * NET + j];
    b1 += ov.y * Wih[(size_t)(e + 1) * NET + j];
    b2 += ov.z * Wih[(size_t)(e + 2) * NET + j];
    b3 += ov.w * Wih[(size_t)(e + 3) * NET + j];
  }
  XW[(size_t)r * NET + j] = (b0 + b1) + (b2 + b3);
}

__global__ __launch_bounds__(256, 1) void k_rnn(
    const float* __restrict__ XW, const float* __restrict__ Whh,
    const float* __restrict__ r1w, const float* __restrict__ r1b,
    const float* __restrict__ r2w, const float* __restrict__ r2b,
    const float* __restrict__ r3w, const float* __restrict__ r3b,
    const float* __restrict__ r4w, const float* __restrict__ r4b,
    float* __restrict__ out) {
  int b = blockIdx.x;
  int tid = threadIdx.x;
  int s = tid & 1;
  int j = tid >> 1;
  __shared__ float xwl[NLQ * NET];
  __shared__ float hb[2][HPAD];
  __shared__ float tmp[HPAD];
  {
    const float4* src = (const float4*)(XW + (size_t)b * NLQ * NET);
    float4* dst = (float4*)xwl;
#pragma unroll
    for (int u = 0; u < 8; u++) dst[tid + 256 * u] = src[tid + 256 * u];
  }
  float w[64];
#pragma unroll
  for (int i = 0; i < 64; i++) w[i] = Whh[(s * 64 + i) * NET + j];
  if (tid < 128) hb[0][PAD(tid)] = 0.f;
  __syncthreads();
  for (int t = 0; t < NLQ; t++) {
    float xwv = xwl[t * NET + j];
    const float4* h4 = (const float4*)&hb[t & 1][s * 68];
    float a0 = 0.f, a1 = 0.f, a2 = 0.f, a3 = 0.f;
#pragma unroll
    for (int i = 0; i < 16; i++) {
      float4 hv = h4[i];
      a0 += hv.x * w[4 * i];
      a1 += hv.y * w[4 * i + 1];
      a2 += hv.z * w[4 * i + 2];
      a3 += hv.w * w[4 * i + 3];
    }
    float acc = (a0 + a1) + (a2 + a3);
    acc += __shfl_xor(acc, 1, 64);
    if (s == 0) {
      float z = acc + xwv;
      float e2 = __expf(2.f * z);
      hb[(t + 1) & 1][PAD(j)] = 1.f - 2.f / (e2 + 1.f);
    }
    __syncthreads();
  }
  layer128(hb[0], r1w, r1b, tmp, j, s);
  __syncthreads();
  layer128(tmp, r2w, r2b, hb[1], j, s);
  __syncthreads();
  layer128(hb[1], r3w, r3b, hb[0], j, s);
  __syncthreads();
  if (tid < 64) {
    int jj = tid >> 3, p = tid & 7;
    float y = 0.f;
#pragma unroll
    for (int i = 0; i < 16; i++) {
      int ii = p * 16 + i;
      y += hb[0][PAD(ii)] * r4w[ii * 8 + jj];
    }
    y += __shfl_xor(y, 1, 64);
    y += __shfl_xor(y, 2, 64);
    y += __shfl_xor(y, 4, 64);
    if (p == 0) out[b * 8 + jj] = y + r4b[jj];
  }
}

// ---------------------------------------------------------------------------
extern "C" void kernel_launch(void* const* d_in, const int* in_sizes, int n_in,
                              void* d_out, int out_size, void* d_ws, size_t ws_size,
                              hipStream_t stream) {
  const float* x     = (const float*)d_in[0];
  const float* ts    = (const float*)d_in[1];
  const float* mask  = (const float*)d_in[2];
  const float* query = (const float*)d_in[3];
  const float* w_lin = (const float*)d_in[4];
  const float* b_lin = (const float*)d_in[5];
  const float* w_per = (const float*)d_in[6];
  const float* b_per = (const float*)d_in[7];
  const float* Wq    = (const float*)d_in[8];
  const float* bq    = (const float*)d_in[9];
  const float* Wk    = (const float*)d_in[10];
  const float* bk    = (const float*)d_in[11];
  const float* Wo    = (const float*)d_in[12];
  const float* bo    = (const float*)d_in[13];
  const float* Wih   = (const float*)d_in[14];
  const float* bih   = (const float*)d_in[15];
  const float* Whh   = (const float*)d_in[16];
  const float* bhh   = (const float*)d_in[17];
  const float* r1w   = (const float*)d_in[18];
  const float* r1b   = (const float*)d_in[19];
  const float* r2w   = (const float*)d_in[20];
  const float* r2b   = (const float*)d_in[21];
  const float* r3w   = (const float*)d_in[22];
  const float* r3b   = (const float*)d_in[23];
  const float* r4w   = (const float*)d_in[24];
  const float* r4b   = (const float*)d_in[25];
  float* out = (float*)d_out;

  float* ws    = (float*)d_ws;
  float* kproj = ws;                         // 524288 f
  float* qproj = ws + 524288;                // 8192 f
  float* XW    = ws + 532480;                // 131072 f
  unsigned* mbg = (unsigned*)(ws + 663552);  // 4096 u32
  float* att   = ws + 667648;                // 262144 f (fallback only)

  static int coop_state = 0;  // 0 = untried, 1 = coop ok, -1 = fallback
  static int nblk = 1024;
  if (coop_state == 0) {
    int mpc = 0;
    if (hipOccupancyMaxActiveBlocksPerMultiprocessor(
            &mpc, (const void*)k_mega, 256, 0) != hipSuccess || mpc < 1)
      mpc = 1;
    long nb = (long)mpc * 256;  // 256 CUs on MI355X
    nblk = (int)(nb > 1024 ? 1024 : nb);
    coop_state = 1;
  }
  if (coop_state == 1) {
    void* args[] = {
        (void*)&x,   (void*)&ts,  (void*)&mask, (void*)&query,
        (void*)&w_lin, (void*)&b_lin, (void*)&w_per, (void*)&b_per,
        (void*)&Wq,  (void*)&bq,  (void*)&Wk,  (void*)&bk,
        (void*)&Wo,  (void*)&bo,  (void*)&Wih, (void*)&bih,
        (void*)&Whh, (void*)&bhh,
        (void*)&r1w, (void*)&r1b, (void*)&r2w, (void*)&r2b,
        (void*)&r3w, (void*)&r3b, (void*)&r4w, (void*)&r4b,
        (void*)&kproj, (void*)&qproj, (void*)&XW, (void*)&mbg,
        (void*)&out};
    hipError_t e = hipLaunchCooperativeKernel(
        (const void*)k_mega, dim3(nblk), dim3(256), args, 0, stream);
    if (e == hipSuccess) return;
    coop_state = -1;  // permanent fallback to 4-kernel pipeline
  }

  k_embed_proj<<<536, 128, 0, stream>>>(
      ts, query, mask, w_lin, b_lin, w_per, b_per, Wk, bk, Wq, bq,
      kproj, qproj, mbg);
  k_attn<<<NB * NH * 16, 256, 0, stream>>>(x, mbg, qproj, kproj, att);
  k_out_xw<<<NB * NLQ, 128, 0, stream>>>(att, Wo, bo, Wih, bih, bhh, XW);
  k_rnn<<<NB, 256, 0, stream>>>(XW, Whh, r1w, r1b, r2w, r2b, r3w, r3b,
                                r4w, r4b, out);
}

// Round 5
// 189.996 us; speedup vs baseline: 2.1885x; 2.1885x over previous
//
#include <hip/hip_runtime.h>
#include <hip/hip_bf16.h>

// All tensors are float32 (verified: runtime dtype probe took the f32 branch).
//
// k_rnn floor note: seven structural variants of the 64-step RNN tie at
// 42-47 us (serial per-step latency at DVFS-reduced clock). Kept verbatim.
//
// R4 post-mortem: cooperative mega-kernel = 400+ us; the two grid.sync()
// barriers cost ~150 us EACH on this runtime (1024-block device-scope spin
// across non-coherent XCD L2s). Cooperative path abandoned permanently.
// Useful residue: the (b,q)-unit attn + fused Wo/Wih epilogue body is
// correctness-verified (mega passed). R5 = R3's 4-kernel pipeline with
// k_attn + k_out_xw merged into that verified body: 3 launches, no att
// global round-trip, epilogues use all 256 threads.

#define NB 16
#define NL 256
#define NLQ 64
#define NDIN 32
#define NET 128
#define NH 4
#define NETK 32

// Padded LDS layout for h/tmp in k_rnn (conflicts verified 0).
#define HPAD 136
#define PAD(i) ((i) + 4 * ((i) >> 6))

// ---------------------------------------------------------------------------
// Kernel 1: time embedding + K/Q projection + mask-bit packing.
// grid = 512 (k-rows) + 8 (q-rows) + 16 (mask pack) = 536 blocks, 128 thr.
// (R3-verbatim)
// ---------------------------------------------------------------------------
__global__ __launch_bounds__(128) void k_embed_proj(
    const float* __restrict__ ts, const float* __restrict__ query,
    const float* __restrict__ mask,
    const float* __restrict__ w_lin, const float* __restrict__ b_lin,
    const float* __restrict__ w_per, const float* __restrict__ b_per,
    const float* __restrict__ Wk, const float* __restrict__ bk,
    const float* __restrict__ Wq, const float* __restrict__ bq,
    float* __restrict__ kproj, float* __restrict__ qproj,
    unsigned* __restrict__ mbg) {
  __shared__ __align__(16) float emb[8 * NET];
  int g = blockIdx.x;
  int j = threadIdx.x;
  if (g >= 520) {  // mask pack: b = g - 520, 2 rows per thread
    int b = g - 520;
#pragma unroll
    for (int half = 0; half < 2; half++) {
      int r = j + 128 * half;
      const float4* mr4 = (const float4*)(mask + (size_t)(b * NL + r) * NDIN);
      unsigned bits = 0;
#pragma unroll
      for (int u = 0; u < 8; u++) {
        float4 m = mr4[u];
        bits |= (m.x != 0.f ? 1u : 0u) << (4 * u);
        bits |= (m.y != 0.f ? 1u : 0u) << (4 * u + 1);
        bits |= (m.z != 0.f ? 1u : 0u) << (4 * u + 2);
        bits |= (m.w != 0.f ? 1u : 0u) << (4 * u + 3);
      }
      mbg[b * NL + r] = bits;
    }
    return;
  }
  bool isQ = (g >= 512);
  int base = (isQ ? g - 512 : g) * 8;
  float wl_ = w_lin[0], bl_ = b_lin[0];
  float wp = (j > 0) ? w_per[j - 1] : 0.f;
  float bp = (j > 0) ? b_per[j - 1] : 0.f;
#pragma unroll
  for (int rr = 0; rr < 8; rr++) {
    float t = isQ ? query[base + rr] : ts[base + rr];
    emb[rr * NET + j] = (j == 0) ? (t * wl_ + bl_) : sinf(t * wp + bp);
  }
  __syncthreads();
  const float* W = isQ ? Wq : Wk;
  float bias = isQ ? bq[j] : bk[j];
  float acc[8];
#pragma unroll
  for (int rr = 0; rr < 8; rr++) acc[rr] = bias;
#pragma unroll 2
  for (int i = 0; i < NET; i += 4) {
    float w0 = W[(size_t)i * NET + j];
    float w1 = W[(size_t)(i + 1) * NET + j];
    float w2 = W[(size_t)(i + 2) * NET + j];
    float w3 = W[(size_t)(i + 3) * NET + j];
#pragma unroll
    for (int rr = 0; rr < 8; rr++) {
      float4 e4 = *(const float4*)&emb[rr * NET + i];
      acc[rr] += e4.x * w0 + e4.y * w1 + e4.z * w2 + e4.w * w3;
    }
  }
  float* dst = isQ ? qproj : kproj;
#pragma unroll
  for (int rr = 0; rr < 8; rr++) dst[(size_t)(base + rr) * NET + j] = acc[rr];
}

// ---------------------------------------------------------------------------
// Kernel 2: attention (all 4 heads) + fused out/xw epilogue.
// block = (b, q). grid = 1024 blocks, 256 threads, ~11 KB LDS.
// Body verified in R4's cooperative run (passed). Masked softmax collapses
// per-channel: att_x = sum(e*m*x)/sum(e*m); all-masked => mean(x), att_m=0.
// Epilogue: orow = arow @ Wo + bo; XW = orow @ Wih + bih + bhh, each split
// across both thread-halves with LDS partial combine.
// ---------------------------------------------------------------------------
__global__ __launch_bounds__(256) void k_attn_oxw(
    const float* __restrict__ x, const unsigned* __restrict__ mbg,
    const float* __restrict__ qproj, const float* __restrict__ kproj,
    const float* __restrict__ Wo, const float* __restrict__ bo,
    const float* __restrict__ Wih, const float* __restrict__ bih,
    const float* __restrict__ bhh, float* __restrict__ XW) {
  const float SC = 0.17677669529663687f;  // 1/sqrt(32)
  int u = blockIdx.x;
  int b = u >> 6, q = u & 63;
  int t = threadIdx.x;

  __shared__ __align__(16) float es[NL * 4];   // [k][h]
  __shared__ float part[3 * 32 * 9];           // phase-B partials
  __shared__ __align__(16) float arow[256];
  __shared__ float po[2][NET];                 // ep1 partials
  __shared__ __align__(16) float orow[NET];
  __shared__ float pw[2][NET];                 // ep2 partials

  // phase A: thread t = key row k; 4 head scores -> one float4 write.
  {
    int k = t;
    const float* kpr = kproj + (size_t)(b * NL + k) * NET;
    float ev[NH];
#pragma unroll
    for (int h = 0; h < NH; h++) {
      float kr[NETK];
      const float4* kp = (const float4*)(kpr + h * NETK);
#pragma unroll
      for (int i = 0; i < 8; i++) {
        float4 v = kp[i];
        kr[4 * i] = v.x; kr[4 * i + 1] = v.y;
        kr[4 * i + 2] = v.z; kr[4 * i + 3] = v.w;
      }
      // block-uniform address -> scalar loads through K-cache
      const float* qv = qproj + (size_t)q * NET + h * NETK;
      float s0 = 0.f, s1 = 0.f;
#pragma unroll
      for (int i = 0; i < NETK; i += 2) {
        s0 += qv[i] * kr[i];
        s1 += qv[i + 1] * kr[i + 1];
      }
      ev[h] = __expf((s0 + s1) * SC);
    }
    *(float4*)&es[k * 4] = make_float4(ev[0], ev[1], ev[2], ev[3]);
  }
  __syncthreads();

  // phase B: thread = (kq = t>>5, c = t&31), 32 k-iters each.
  float den[NH] = {0.f, 0.f, 0.f, 0.f};
  float num[NH] = {0.f, 0.f, 0.f, 0.f};
  float sumx = 0.f;
  int c = t & 31;
  {
    int kq = t >> 5;
    const float* xb = x + (size_t)b * NL * NDIN;
    const unsigned* mbb = mbg + b * NL;
    int k0 = kq * 32;
#pragma unroll 4
    for (int kk = 0; kk < 32; kk++) {
      int k = k0 + kk;
      float4 e4 = *(const float4*)&es[k * 4];
      float xv = xb[(size_t)k * NDIN + c];
      float mv = ((mbb[k] >> c) & 1u) ? 1.f : 0.f;
      sumx += xv;
      float e0 = e4.x * mv, e1 = e4.y * mv, e2 = e4.z * mv, e3 = e4.w * mv;
      den[0] += e0; num[0] += e0 * xv;
      den[1] += e1; num[1] += e1 * xv;
      den[2] += e2; num[2] += e2 * xv;
      den[3] += e3; num[3] += e3 * xv;
    }
  }
  sumx += __shfl_xor(sumx, 32, 64);
#pragma unroll
  for (int hh = 0; hh < NH; hh++) {
    den[hh] += __shfl_xor(den[hh], 32, 64);
    num[hh] += __shfl_xor(num[hh], 32, 64);
  }
  {
    int w = t >> 6, l = t & 63;
    if (w > 0 && l < 32) {
      float* p = &part[((w - 1) * 32 + c) * 9];  // stride 9: conflict-free
#pragma unroll
      for (int hh = 0; hh < NH; hh++) { p[hh] = den[hh]; p[4 + hh] = num[hh]; }
      p[8] = sumx;
    }
  }
  __syncthreads();
  if (t < 32) {
#pragma unroll
    for (int ww = 0; ww < 3; ww++) {
      const float* p = &part[(ww * 32 + t) * 9];
#pragma unroll
      for (int hh = 0; hh < NH; hh++) { den[hh] += p[hh]; num[hh] += p[4 + hh]; }
      sumx += p[8];
    }
    float meanx = sumx * (1.f / 256.f);
#pragma unroll
    for (int hh = 0; hh < NH; hh++) {
      bool any = (den[hh] > 0.f);
      arow[hh * 64 + t]      = any ? (num[hh] / den[hh]) : meanx;
      arow[hh * 64 + 32 + t] = any ? 1.f : 0.f;
    }
  }
  __syncthreads();

  // epilogue 1 (all 256 thr): po[half][j] = sum_{u in half*128..+128}
  // arow[u]*Wo[u][j]; then orow[j] = po[0][j]+po[1][j]+bo[j].
  {
    int j = t & 127, half = t >> 7;
    int u0 = half * 128;
    float o0 = 0.f, o1 = 0.f, o2 = 0.f, o3 = 0.f;
#pragma unroll 4
    for (int uu = u0; uu < u0 + 128; uu += 4) {
      float4 av = *(const float4*)&arow[uu];
      o0 += av.x * Wo[(size_t)uu * NET + j];
      o1 += av.y * Wo[(size_t)(uu + 1) * NET + j];
      o2 += av.z * Wo[(size_t)(uu + 2) * NET + j];
      o3 += av.w * Wo[(size_t)(uu + 3) * NET + j];
    }
    po[half][j] = (o0 + o1) + (o2 + o3);
  }
  __syncthreads();
  if (t < 128) orow[t] = po[0][t] + po[1][t] + bo[t];
  __syncthreads();

  // epilogue 2 (all 256 thr): pw[half][j] = sum_{e in half*64..+64}
  // orow[e]*Wih[e][j]; then XW = pw[0]+pw[1]+bih+bhh.
  {
    int j = t & 127, half = t >> 7;
    int e0 = half * 64;
    float a0 = 0.f, a1 = 0.f, a2 = 0.f, a3 = 0.f;
#pragma unroll 4
    for (int e = e0; e < e0 + 64; e += 4) {
      float4 ov = *(const float4*)&orow[e];
      a0 += ov.x * Wih[(size_t)e * NET + j];
      a1 += ov.y * Wih[(size_t)(e + 1) * NET + j];
      a2 += ov.z * Wih[(size_t)(e + 2) * NET + j];
      a3 += ov.w * Wih[(size_t)(e + 3) * NET + j];
    }
    pw[half][j] = (a0 + a1) + (a2 + a3);
  }
  __syncthreads();
  if (t < 128)
    XW[(size_t)(b * NLQ + q) * NET + t] =
        pw[0][t] + pw[1][t] + bih[t] + bhh[t];
}

// ---------------------------------------------------------------------------
// helper: dst[PAD(j)] = b[j] + sum_i src[i] * W[i*128+j], split-2 over s.
// ---------------------------------------------------------------------------
__device__ __forceinline__ void layer128(const float* src_lds,
                                         const float* __restrict__ W,
                                         const float* __restrict__ bvec,
                                         float* dst_lds, int j, int s) {
  const float4* h4 = (const float4*)(src_lds + s * 68);
  float a0 = 0.f, a1 = 0.f, a2 = 0.f, a3 = 0.f;
#pragma unroll
  for (int i = 0; i < 16; i++) {
    float4 hv = h4[i];
    int base = (s * 64 + 4 * i) * NET + j;
    a0 += hv.x * W[base];
    a1 += hv.y * W[base + NET];
    a2 += hv.z * W[base + 2 * NET];
    a3 += hv.w * W[base + 3 * NET];
  }
  float acc = (a0 + a1) + (a2 + a3);
  acc += __shfl_xor(acc, 1, 64);
  if (s == 0) dst_lds[PAD(j)] = acc + bvec[j];
}

// ---------------------------------------------------------------------------
// Kernel 3: sequential RNN (64 steps) + regressor. grid = 16, 256 threads.
// Kept verbatim (measured floor ~42-45 us).
// ---------------------------------------------------------------------------
__global__ __launch_bounds__(256, 1) void k_rnn(
    const float* __restrict__ XW, const float* __restrict__ Whh,
    const float* __restrict__ r1w, const float* __restrict__ r1b,
    const float* __restrict__ r2w, const float* __restrict__ r2b,
    const float* __restrict__ r3w, const float* __restrict__ r3b,
    const float* __restrict__ r4w, const float* __restrict__ r4b,
    float* __restrict__ out) {
  int b = blockIdx.x;
  int tid = threadIdx.x;
  int s = tid & 1;
  int j = tid >> 1;
  __shared__ float xwl[NLQ * NET];  // 32 KB, staged once
  __shared__ float hb[2][HPAD];
  __shared__ float tmp[HPAD];
  {
    const float4* src = (const float4*)(XW + (size_t)b * NLQ * NET);
    float4* dst = (float4*)xwl;
#pragma unroll
    for (int u = 0; u < 8; u++) dst[tid + 256 * u] = src[tid + 256 * u];
  }
  float w[64];
#pragma unroll
  for (int i = 0; i < 64; i++) w[i] = Whh[(s * 64 + i) * NET + j];
  if (tid < 128) hb[0][PAD(tid)] = 0.f;
  __syncthreads();
  for (int t = 0; t < NLQ; t++) {
    float xwv = xwl[t * NET + j];
    const float4* h4 = (const float4*)&hb[t & 1][s * 68];
    float a0 = 0.f, a1 = 0.f, a2 = 0.f, a3 = 0.f;
#pragma unroll
    for (int i = 0; i < 16; i++) {
      float4 hv = h4[i];
      a0 += hv.x * w[4 * i];
      a1 += hv.y * w[4 * i + 1];
      a2 += hv.z * w[4 * i + 2];
      a3 += hv.w * w[4 * i + 3];
    }
    float acc = (a0 + a1) + (a2 + a3);
    acc += __shfl_xor(acc, 1, 64);
    if (s == 0) {
      float z = acc + xwv;
      float e2 = __expf(2.f * z);
      hb[(t + 1) & 1][PAD(j)] = 1.f - 2.f / (e2 + 1.f);  // tanh(z)
    }
    __syncthreads();
  }
  layer128(hb[0], r1w, r1b, tmp, j, s);
  __syncthreads();
  layer128(tmp, r2w, r2b, hb[1], j, s);
  __syncthreads();
  layer128(hb[1], r3w, r3b, hb[0], j, s);
  __syncthreads();
  if (tid < 64) {
    int jj = tid >> 3, p = tid & 7;
    float y = 0.f;
#pragma unroll
    for (int i = 0; i < 16; i++) {
      int ii = p * 16 + i;
      y += hb[0][PAD(ii)] * r4w[ii * 8 + jj];
    }
    y += __shfl_xor(y, 1, 64);
    y += __shfl_xor(y, 2, 64);
    y += __shfl_xor(y, 4, 64);
    if (p == 0) out[b * 8 + jj] = y + r4b[jj];
  }
}

// ---------------------------------------------------------------------------
extern "C" void kernel_launch(void* const* d_in, const int* in_sizes, int n_in,
                              void* d_out, int out_size, void* d_ws, size_t ws_size,
                              hipStream_t stream) {
  const float* x     = (const float*)d_in[0];
  const float* ts    = (const float*)d_in[1];
  const float* mask  = (const float*)d_in[2];
  const float* query = (const float*)d_in[3];
  const float* w_lin = (const float*)d_in[4];
  const float* b_lin = (const float*)d_in[5];
  const float* w_per = (const float*)d_in[6];
  const float* b_per = (const float*)d_in[7];
  const float* Wq    = (const float*)d_in[8];
  const float* bq    = (const float*)d_in[9];
  const float* Wk    = (const float*)d_in[10];
  const float* bk    = (const float*)d_in[11];
  const float* Wo    = (const float*)d_in[12];
  const float* bo    = (const float*)d_in[13];
  const float* Wih   = (const float*)d_in[14];
  const float* bih   = (const float*)d_in[15];
  const float* Whh   = (const float*)d_in[16];
  const float* bhh   = (const float*)d_in[17];
  const float* r1w   = (const float*)d_in[18];
  const float* r1b   = (const float*)d_in[19];
  const float* r2w   = (const float*)d_in[20];
  const float* r2b   = (const float*)d_in[21];
  const float* r3w   = (const float*)d_in[22];
  const float* r3b   = (const float*)d_in[23];
  const float* r4w   = (const float*)d_in[24];
  const float* r4b   = (const float*)d_in[25];
  float* out = (float*)d_out;

  float* ws    = (float*)d_ws;
  float* kproj = ws;                         // 524288 f
  float* qproj = ws + 524288;                // 8192 f
  float* XW    = ws + 532480;                // 131072 f
  unsigned* mbg = (unsigned*)(ws + 663552);  // 4096 u32

  k_embed_proj<<<536, 128, 0, stream>>>(
      ts, query, mask, w_lin, b_lin, w_per, b_per, Wk, bk, Wq, bq,
      kproj, qproj, mbg);
  k_attn_oxw<<<NB * NLQ, 256, 0, stream>>>(
      x, mbg, qproj, kproj, Wo, bo, Wih, bih, bhh, XW);
  k_rnn<<<NB, 256, 0, stream>>>(XW, Whh, r1w, r1b, r2w, r2b, r3w, r3b,
                                r4w, r4b, out);
}

// Round 6
// 173.335 us; speedup vs baseline: 2.3989x; 1.0961x over previous
//
#include <hip/hip_runtime.h>
#include <hip/hip_bf16.h>

// All tensors are float32 (verified: runtime dtype probe took the f32 branch).
//
// Session accounting (R0-R5): total ~179-190 us = fill(41, harness-fixed) +
// k_rnn(44, serial-latency floor: 7+ structural variants tie 42-47) +
// embed/attn/out_xw (each <15) + reset/gap overhead (~50-60, harness-fixed).
// R4: cooperative grid.sync costs ~150 us each -> mega-kernel dead.
// R5: (b,q)-fused attn+oxw = net neutral/negative (4x kproj re-read ~ saved
// gap); R3's 4-kernel structure is the measured best (178.9).
// R6 = R3 structure verbatim + packed-f32 (v_pk_fma_f32) in the k_rnn step
// dot and k_attn phase-B inner loop. Pre-commit: if k_rnn stays 44+-1, the
// rnn barrier/LDS-latency floor is confirmed and the kernel is closed.

#define NB 16
#define NL 256
#define NLQ 64
#define NDIN 32
#define NET 128
#define NH 4
#define NETK 32

// Padded LDS layout for h/tmp in k_rnn (conflicts verified 0).
#define HPAD 136
#define PAD(i) ((i) + 4 * ((i) >> 6))

typedef float f32x2 __attribute__((ext_vector_type(2)));

// ---------------------------------------------------------------------------
// Kernel 1: time embedding + K/Q projection + mask-bit packing.
// grid = 512 (k-rows) + 8 (q-rows) + 16 (mask pack) = 536 blocks, 128 thr.
// (R3-verbatim)
// ---------------------------------------------------------------------------
__global__ __launch_bounds__(128) void k_embed_proj(
    const float* __restrict__ ts, const float* __restrict__ query,
    const float* __restrict__ mask,
    const float* __restrict__ w_lin, const float* __restrict__ b_lin,
    const float* __restrict__ w_per, const float* __restrict__ b_per,
    const float* __restrict__ Wk, const float* __restrict__ bk,
    const float* __restrict__ Wq, const float* __restrict__ bq,
    float* __restrict__ kproj, float* __restrict__ qproj,
    unsigned* __restrict__ mbg) {
  __shared__ __align__(16) float emb[8 * NET];
  int g = blockIdx.x;
  int j = threadIdx.x;
  if (g >= 520) {  // mask pack: b = g - 520, 2 rows per thread
    int b = g - 520;
#pragma unroll
    for (int half = 0; half < 2; half++) {
      int r = j + 128 * half;
      const float4* mr4 = (const float4*)(mask + (size_t)(b * NL + r) * NDIN);
      unsigned bits = 0;
#pragma unroll
      for (int u = 0; u < 8; u++) {
        float4 m = mr4[u];
        bits |= (m.x != 0.f ? 1u : 0u) << (4 * u);
        bits |= (m.y != 0.f ? 1u : 0u) << (4 * u + 1);
        bits |= (m.z != 0.f ? 1u : 0u) << (4 * u + 2);
        bits |= (m.w != 0.f ? 1u : 0u) << (4 * u + 3);
      }
      mbg[b * NL + r] = bits;
    }
    return;
  }
  bool isQ = (g >= 512);
  int base = (isQ ? g - 512 : g) * 8;
  float wl_ = w_lin[0], bl_ = b_lin[0];
  float wp = (j > 0) ? w_per[j - 1] : 0.f;
  float bp = (j > 0) ? b_per[j - 1] : 0.f;
#pragma unroll
  for (int rr = 0; rr < 8; rr++) {
    float t = isQ ? query[base + rr] : ts[base + rr];
    emb[rr * NET + j] = (j == 0) ? (t * wl_ + bl_) : sinf(t * wp + bp);
  }
  __syncthreads();
  const float* W = isQ ? Wq : Wk;
  float bias = isQ ? bq[j] : bk[j];
  float acc[8];
#pragma unroll
  for (int rr = 0; rr < 8; rr++) acc[rr] = bias;
#pragma unroll 2
  for (int i = 0; i < NET; i += 4) {
    float w0 = W[(size_t)i * NET + j];
    float w1 = W[(size_t)(i + 1) * NET + j];
    float w2 = W[(size_t)(i + 2) * NET + j];
    float w3 = W[(size_t)(i + 3) * NET + j];
#pragma unroll
    for (int rr = 0; rr < 8; rr++) {
      float4 e4 = *(const float4*)&emb[rr * NET + i];
      acc[rr] += e4.x * w0 + e4.y * w1 + e4.z * w2 + e4.w * w3;
    }
  }
  float* dst = isQ ? qproj : kproj;
#pragma unroll
  for (int rr = 0; rr < 8; rr++) dst[(size_t)(base + rr) * NET + j] = acc[rr];
}

// ---------------------------------------------------------------------------
// Kernel 2: attention. block = (b, h, qgroup of 4). grid = 1024, 256 thr.
// LDS 7.4 KB -> 4 blocks/CU, 16 waves/CU. es4[k] = all 4 qq exps (float4):
// phase B does 1 ds_read_b128 + 2 global loads per k for 9 FMA-equivalents
// (packed f32x2). Masked softmax collapses per-channel:
// att_x = sum(e*m*x)/sum(e*m); all-masked channel => mean(x), att_m = 0.
// ---------------------------------------------------------------------------
__global__ __launch_bounds__(256) void k_attn(
    const float* __restrict__ x, const unsigned* __restrict__ mbg,
    const float* __restrict__ qproj, const float* __restrict__ kproj,
    float* __restrict__ att) {
  const float SC = 0.17677669529663687f;  // 1/sqrt(32)
  int blk = blockIdx.x;
  int qg = blk & 15;
  int h  = (blk >> 4) & 3;
  int b  = blk >> 6;
  int t  = threadIdx.x;

  __shared__ __align__(16) float es4[NL * 4];  // 4 KB: [k][qq]
  __shared__ float part[3 * 32 * 9];           // 3.4 KB: [wave-1][c][9]

  // phase A: thread t = key row k. 4 qq scores -> one float4 write.
  {
    int k = t;
    float kr[NETK];
    const float4* kp =
        (const float4*)(kproj + (size_t)(b * NL + k) * NET + h * NETK);
#pragma unroll
    for (int i = 0; i < 8; i++) {
      float4 v = kp[i];
      kr[4 * i] = v.x; kr[4 * i + 1] = v.y;
      kr[4 * i + 2] = v.z; kr[4 * i + 3] = v.w;
    }
    float ev[4];
#pragma unroll
    for (int qq = 0; qq < 4; qq++) {
      // wave-uniform address -> scalar loads through K-cache
      const float* qv = qproj + (size_t)(qg * 4 + qq) * NET + h * NETK;
      float s0 = 0.f, s1 = 0.f;
#pragma unroll
      for (int i = 0; i < NETK; i += 2) {
        s0 += qv[i] * kr[i];
        s1 += qv[i + 1] * kr[i + 1];
      }
      ev[qq] = __expf((s0 + s1) * SC);
    }
    *(float4*)&es4[k * 4] = make_float4(ev[0], ev[1], ev[2], ev[3]);
  }
  __syncthreads();

  // phase B: thread = (kq = t>>5, c = t&31), 32 k-iters each. Packed f32x2
  // accumulators (v_pk_fma_f32): den/num pairs in vector lanes.
  int kq = t >> 5, c = t & 31;
  f32x2 den01 = {0.f, 0.f}, den23 = {0.f, 0.f};
  f32x2 num01 = {0.f, 0.f}, num23 = {0.f, 0.f};
  float sumx = 0.f;
  {
    const float* xb = x + (size_t)b * NL * NDIN;
    const unsigned* mbb = mbg + b * NL;
    int k0 = kq * 32;
#pragma unroll 4
    for (int kk = 0; kk < 32; kk++) {
      int k = k0 + kk;
      float4 e4 = *(const float4*)&es4[k * 4];
      float xv = xb[(size_t)k * NDIN + c];
      float mv = ((mbb[k] >> c) & 1u) ? 1.f : 0.f;
      sumx += xv;
      f32x2 e01 = (f32x2){e4.x, e4.y} * mv;   // v_pk_mul
      f32x2 e23 = (f32x2){e4.z, e4.w} * mv;
      den01 += e01;                            // v_pk_add
      den23 += e23;
      num01 += e01 * xv;                       // v_pk_fma (contract)
      num23 += e23 * xv;
    }
  }
  float den[4] = {den01.x, den01.y, den23.x, den23.y};
  float num[4] = {num01.x, num01.y, num23.x, num23.y};
  // combine kq pairs within the wave (lane l <-> l+32 differ only in kq)
  sumx += __shfl_xor(sumx, 32, 64);
#pragma unroll
  for (int q = 0; q < 4; q++) {
    den[q] += __shfl_xor(den[q], 32, 64);
    num[q] += __shfl_xor(num[q], 32, 64);
  }
  // waves 1..3 publish partials (stride 9 -> conflict-free)
  {
    int w = t >> 6, lane = t & 63;
    if (w > 0 && lane < 32) {
      float* p = &part[((w - 1) * 32 + c) * 9];
#pragma unroll
      for (int q = 0; q < 4; q++) { p[q] = den[q]; p[4 + q] = num[q]; }
      p[8] = sumx;
    }
  }
  __syncthreads();

  // wave 0 lanes 0-31 combine + finalize
  if (t < 32) {
#pragma unroll
    for (int ww = 0; ww < 3; ww++) {
      const float* p = &part[(ww * 32 + t) * 9];
#pragma unroll
      for (int q = 0; q < 4; q++) { den[q] += p[q]; num[q] += p[4 + q]; }
      sumx += p[8];
    }
    float meanx = sumx * (1.f / 256.f);
#pragma unroll
    for (int qq = 0; qq < 4; qq++) {
      bool any = (den[qq] > 0.f);
      float* ao =
          att + (size_t)(((b * NLQ + qg * 4 + qq) * NH) + h) * 64;
      ao[t]      = any ? (num[qq] / den[qq]) : meanx;
      ao[32 + t] = any ? 1.f : 0.f;
    }
  }
}

// ---------------------------------------------------------------------------
// Kernel 3: out = att @ Wo + bo; XW = out @ W_ih + b_ih + b_hh.
// grid = B*LQ = 1024 blocks, 128 threads. (R3-verbatim)
// ---------------------------------------------------------------------------
__global__ __launch_bounds__(128) void k_out_xw(
    const float* __restrict__ att,
    const float* __restrict__ Wo, const float* __restrict__ bo,
    const float* __restrict__ Wih, const float* __restrict__ bih,
    const float* __restrict__ bhh, float* __restrict__ XW) {
  int r = blockIdx.x;
  int j = threadIdx.x;
  __shared__ __align__(16) float arow[NH * 64];
  __shared__ __align__(16) float orow[NET];
  arow[j]       = att[(size_t)r * 256 + j];
  arow[j + 128] = att[(size_t)r * 256 + 128 + j];
  __syncthreads();
  float a0 = bo[j], a1 = 0.f, a2 = 0.f, a3 = 0.f;
#pragma unroll 4
  for (int u = 0; u < 256; u += 4) {
    float4 av = *(const float4*)&arow[u];
    a0 += av.x * Wo[(size_t)u * NET + j];
    a1 += av.y * Wo[(size_t)(u + 1) * NET + j];
    a2 += av.z * Wo[(size_t)(u + 2) * NET + j];
    a3 += av.w * Wo[(size_t)(u + 3) * NET + j];
  }
  orow[j] = (a0 + a1) + (a2 + a3);
  __syncthreads();
  float b0 = bih[j] + bhh[j], b1 = 0.f, b2 = 0.f, b3 = 0.f;
#pragma unroll 4
  for (int e = 0; e < NET; e += 4) {
    float4 ov = *(const float4*)&orow[e];
    b0 += ov.x * Wih[(size_t)e * NET + j];
    b1 += ov.y * Wih[(size_t)(e + 1) * NET + j];
    b2 += ov.z * Wih[(size_t)(e + 2) * NET + j];
    b3 += ov.w * Wih[(size_t)(e + 3) * NET + j];
  }
  XW[(size_t)r * NET + j] = (b0 + b1) + (b2 + b3);
}

// ---------------------------------------------------------------------------
// helper: dst[PAD(j)] = b[j] + sum_i src[i] * W[i*128+j], split-2 over s.
// ---------------------------------------------------------------------------
__device__ __forceinline__ void layer128(const float* src_lds,
                                         const float* __restrict__ W,
                                         const float* __restrict__ bvec,
                                         float* dst_lds, int j, int s) {
  const float4* h4 = (const float4*)(src_lds + s * 68);
  float a0 = 0.f, a1 = 0.f, a2 = 0.f, a3 = 0.f;
#pragma unroll
  for (int i = 0; i < 16; i++) {
    float4 hv = h4[i];
    int base = (s * 64 + 4 * i) * NET + j;
    a0 += hv.x * W[base];
    a1 += hv.y * W[base + NET];
    a2 += hv.z * W[base + 2 * NET];
    a3 += hv.w * W[base + 3 * NET];
  }
  float acc = (a0 + a1) + (a2 + a3);
  acc += __shfl_xor(acc, 1, 64);
  if (s == 0) dst_lds[PAD(j)] = acc + bvec[j];
}

// ---------------------------------------------------------------------------
// Kernel 4: sequential RNN (64 steps) + regressor. grid = 16, 256 threads.
// Structure verbatim from the measured-floor configuration; step dot now
// uses packed f32x2 FMA (32 v_pk_fma_f32 instead of 64 v_fma_f32).
// ---------------------------------------------------------------------------
__global__ __launch_bounds__(256, 1) void k_rnn(
    const float* __restrict__ XW, const float* __restrict__ Whh,
    const float* __restrict__ r1w, const float* __restrict__ r1b,
    const float* __restrict__ r2w, const float* __restrict__ r2b,
    const float* __restrict__ r3w, const float* __restrict__ r3b,
    const float* __restrict__ r4w, const float* __restrict__ r4b,
    float* __restrict__ out) {
  int b = blockIdx.x;
  int tid = threadIdx.x;
  int s = tid & 1;
  int j = tid >> 1;
  __shared__ float xwl[NLQ * NET];  // 32 KB, staged once
  __shared__ float hb[2][HPAD];
  __shared__ float tmp[HPAD];
  {
    const float4* src = (const float4*)(XW + (size_t)b * NLQ * NET);
    float4* dst = (float4*)xwl;
#pragma unroll
    for (int u = 0; u < 8; u++) dst[tid + 256 * u] = src[tid + 256 * u];
  }
  // Whh half-column as 32 packed f32x2 (constant indices after unroll)
  f32x2 w2[32];
#pragma unroll
  for (int i = 0; i < 32; i++) {
    w2[i].x = Whh[(s * 64 + 2 * i) * NET + j];
    w2[i].y = Whh[(s * 64 + 2 * i + 1) * NET + j];
  }
  if (tid < 128) hb[0][PAD(tid)] = 0.f;
  __syncthreads();
  for (int t = 0; t < NLQ; t++) {
    float xwv = xwl[t * NET + j];
    const float4* h4 = (const float4*)&hb[t & 1][s * 68];
    f32x2 accA = {0.f, 0.f}, accB = {0.f, 0.f};
#pragma unroll
    for (int i = 0; i < 16; i++) {
      float4 hv = h4[i];
      accA += (f32x2){hv.x, hv.y} * w2[2 * i];      // v_pk_fma_f32
      accB += (f32x2){hv.z, hv.w} * w2[2 * i + 1];
    }
    float acc = (accA.x + accA.y) + (accB.x + accB.y);
    acc += __shfl_xor(acc, 1, 64);
    if (s == 0) {
      float z = acc + xwv;
      float e2 = __expf(2.f * z);
      hb[(t + 1) & 1][PAD(j)] = 1.f - 2.f / (e2 + 1.f);  // tanh(z)
    }
    __syncthreads();
  }
  layer128(hb[0], r1w, r1b, tmp, j, s);
  __syncthreads();
  layer128(tmp, r2w, r2b, hb[1], j, s);
  __syncthreads();
  layer128(hb[1], r3w, r3b, hb[0], j, s);
  __syncthreads();
  if (tid < 64) {
    int jj = tid >> 3, p = tid & 7;
    float y = 0.f;
#pragma unroll
    for (int i = 0; i < 16; i++) {
      int ii = p * 16 + i;
      y += hb[0][PAD(ii)] * r4w[ii * 8 + jj];
    }
    y += __shfl_xor(y, 1, 64);
    y += __shfl_xor(y, 2, 64);
    y += __shfl_xor(y, 4, 64);
    if (p == 0) out[b * 8 + jj] = y + r4b[jj];
  }
}

// ---------------------------------------------------------------------------
extern "C" void kernel_launch(void* const* d_in, const int* in_sizes, int n_in,
                              void* d_out, int out_size, void* d_ws, size_t ws_size,
                              hipStream_t stream) {
  const float* x     = (const float*)d_in[0];
  const float* ts    = (const float*)d_in[1];
  const float* mask  = (const float*)d_in[2];
  const float* query = (const float*)d_in[3];
  const float* w_lin = (const float*)d_in[4];
  const float* b_lin = (const float*)d_in[5];
  const float* w_per = (const float*)d_in[6];
  const float* b_per = (const float*)d_in[7];
  const float* Wq    = (const float*)d_in[8];
  const float* bq    = (const float*)d_in[9];
  const float* Wk    = (const float*)d_in[10];
  const float* bk    = (const float*)d_in[11];
  const float* Wo    = (const float*)d_in[12];
  const float* bo    = (const float*)d_in[13];
  const float* Wih   = (const float*)d_in[14];
  const float* bih   = (const float*)d_in[15];
  const float* Whh   = (const float*)d_in[16];
  const float* bhh   = (const float*)d_in[17];
  const float* r1w   = (const float*)d_in[18];
  const float* r1b   = (const float*)d_in[19];
  const float* r2w   = (const float*)d_in[20];
  const float* r2b   = (const float*)d_in[21];
  const float* r3w   = (const float*)d_in[22];
  const float* r3b   = (const float*)d_in[23];
  const float* r4w   = (const float*)d_in[24];
  const float* r4b   = (const float*)d_in[25];
  float* out = (float*)d_out;

  float* ws    = (float*)d_ws;
  float* kproj = ws;                         // 524288 f
  float* qproj = ws + 524288;                // 8192 f
  float* att   = ws + 532480;                // 262144 f
  float* XW    = ws + 794624;                // 131072 f
  unsigned* mbg = (unsigned*)(ws + 925696);  // 4096 u32

  k_embed_proj<<<536, 128, 0, stream>>>(
      ts, query, mask, w_lin, b_lin, w_per, b_per, Wk, bk, Wq, bq,
      kproj, qproj, mbg);
  k_attn<<<NB * NH * 16, 256, 0, stream>>>(x, mbg, qproj, kproj, att);
  k_out_xw<<<NB * NLQ, 128, 0, stream>>>(att, Wo, bo, Wih, bih, bhh, XW);
  k_rnn<<<NB, 256, 0, stream>>>(XW, Whh, r1w, r1b, r2w, r2b, r3w, r3b,
                                r4w, r4b, out);
}

// Round 7
// 172.122 us; speedup vs baseline: 2.4158x; 1.0071x over previous
//
#include <hip/hip_runtime.h>
#include <hip/hip_bf16.h>

// All tensors are float32 (verified: runtime dtype probe took the f32 branch).
//
// Session accounting (R0-R6): total 173-190 us = fill(41, harness-fixed) +
// k_rnn + embed/attn/oxw + reset/gap overhead (~60, harness-fixed).
// R4: cooperative grid.sync costs ~150 us each -> mega-kernel dead.
// R5: (b,q)-fused attn+oxw net-neutral; R3 4-kernel structure is best.
// R6: pk-FMA (v_pk_fma_f32) in k_rnn step dot took k_rnn 44.5 -> <=41
// (out of top-5): the rnn step is partly VALU-ISSUE-bound, not pure
// latency. R7 pushes the same lever: k_rnn 4-way split (512 thr, 32-elem
// dots, 16 f32x2 weights -> register-resident), pk in embed inner loop,
// pk in out_xw (bit-identical tree), pk in attn phase A.
// Pre-commit: if total >= 172, controllable floor reached -> ROOFLINE.

#define NB 16
#define NL 256
#define NLQ 64
#define NDIN 32
#define NET 128
#define NH 4
#define NETK 32

// Padded LDS layout for h/tmp in k_rnn (conflicts verified 0).
#define HPAD 136
#define PAD(i) ((i) + 4 * ((i) >> 6))

typedef float f32x2 __attribute__((ext_vector_type(2)));

// ---------------------------------------------------------------------------
// Kernel 1: time embedding + K/Q projection + mask-bit packing.
// grid = 512 (k-rows) + 8 (q-rows) + 16 (mask pack) = 536 blocks, 128 thr.
// Inner product loop pk-ified: 2 v_pk_fma per 4-i group per row.
// ---------------------------------------------------------------------------
__global__ __launch_bounds__(128) void k_embed_proj(
    const float* __restrict__ ts, const float* __restrict__ query,
    const float* __restrict__ mask,
    const float* __restrict__ w_lin, const float* __restrict__ b_lin,
    const float* __restrict__ w_per, const float* __restrict__ b_per,
    const float* __restrict__ Wk, const float* __restrict__ bk,
    const float* __restrict__ Wq, const float* __restrict__ bq,
    float* __restrict__ kproj, float* __restrict__ qproj,
    unsigned* __restrict__ mbg) {
  __shared__ __align__(16) float emb[8 * NET];
  int g = blockIdx.x;
  int j = threadIdx.x;
  if (g >= 520) {  // mask pack: b = g - 520, 2 rows per thread
    int b = g - 520;
#pragma unroll
    for (int half = 0; half < 2; half++) {
      int r = j + 128 * half;
      const float4* mr4 = (const float4*)(mask + (size_t)(b * NL + r) * NDIN);
      unsigned bits = 0;
#pragma unroll
      for (int u = 0; u < 8; u++) {
        float4 m = mr4[u];
        bits |= (m.x != 0.f ? 1u : 0u) << (4 * u);
        bits |= (m.y != 0.f ? 1u : 0u) << (4 * u + 1);
        bits |= (m.z != 0.f ? 1u : 0u) << (4 * u + 2);
        bits |= (m.w != 0.f ? 1u : 0u) << (4 * u + 3);
      }
      mbg[b * NL + r] = bits;
    }
    return;
  }
  bool isQ = (g >= 512);
  int base = (isQ ? g - 512 : g) * 8;
  float wl_ = w_lin[0], bl_ = b_lin[0];
  float wp = (j > 0) ? w_per[j - 1] : 0.f;
  float bp = (j > 0) ? b_per[j - 1] : 0.f;
#pragma unroll
  for (int rr = 0; rr < 8; rr++) {
    float t = isQ ? query[base + rr] : ts[base + rr];
    emb[rr * NET + j] = (j == 0) ? (t * wl_ + bl_) : sinf(t * wp + bp);
  }
  __syncthreads();
  const float* W = isQ ? Wq : Wk;
  float bias = isQ ? bq[j] : bk[j];
  f32x2 acc2[8];
#pragma unroll
  for (int rr = 0; rr < 8; rr++) acc2[rr] = (f32x2){bias, 0.f};
#pragma unroll 2
  for (int i = 0; i < NET; i += 4) {
    f32x2 wA = {W[(size_t)i * NET + j], W[(size_t)(i + 1) * NET + j]};
    f32x2 wB = {W[(size_t)(i + 2) * NET + j], W[(size_t)(i + 3) * NET + j]};
#pragma unroll
    for (int rr = 0; rr < 8; rr++) {
      float4 e4 = *(const float4*)&emb[rr * NET + i];
      acc2[rr] += (f32x2){e4.x, e4.y} * wA;   // v_pk_fma_f32
      acc2[rr] += (f32x2){e4.z, e4.w} * wB;
    }
  }
  float* dst = isQ ? qproj : kproj;
#pragma unroll
  for (int rr = 0; rr < 8; rr++)
    dst[(size_t)(base + rr) * NET + j] = acc2[rr].x + acc2[rr].y;
}

// ---------------------------------------------------------------------------
// Kernel 2: attention. block = (b, h, qgroup of 4). grid = 1024, 256 thr.
// LDS 7.4 KB -> 4 blocks/CU, 16 waves/CU. es4[k] = all 4 qq exps (float4):
// phase B does 1 ds_read_b128 + 2 global loads per k, packed f32x2 math.
// Masked softmax collapses per-channel: att_x = sum(e*m*x)/sum(e*m);
// all-masked channel => mean(x), att_m = 0.
// ---------------------------------------------------------------------------
__global__ __launch_bounds__(256) void k_attn(
    const float* __restrict__ x, const unsigned* __restrict__ mbg,
    const float* __restrict__ qproj, const float* __restrict__ kproj,
    float* __restrict__ att) {
  const float SC = 0.17677669529663687f;  // 1/sqrt(32)
  int blk = blockIdx.x;
  int qg = blk & 15;
  int h  = (blk >> 4) & 3;
  int b  = blk >> 6;
  int t  = threadIdx.x;

  __shared__ __align__(16) float es4[NL * 4];  // 4 KB: [k][qq]
  __shared__ float part[3 * 32 * 9];           // 3.4 KB: [wave-1][c][9]

  // phase A: thread t = key row k. 4 qq scores -> one float4 write.
  {
    int k = t;
    float kr[NETK];
    const float4* kp =
        (const float4*)(kproj + (size_t)(b * NL + k) * NET + h * NETK);
#pragma unroll
    for (int i = 0; i < 8; i++) {
      float4 v = kp[i];
      kr[4 * i] = v.x; kr[4 * i + 1] = v.y;
      kr[4 * i + 2] = v.z; kr[4 * i + 3] = v.w;
    }
    float ev[4];
#pragma unroll
    for (int qq = 0; qq < 4; qq++) {
      // wave-uniform address -> scalar loads through K-cache
      const float* qv = qproj + (size_t)(qg * 4 + qq) * NET + h * NETK;
      f32x2 s2 = {0.f, 0.f};
#pragma unroll
      for (int i = 0; i < NETK; i += 2)
        s2 += (f32x2){qv[i], qv[i + 1]} * (f32x2){kr[i], kr[i + 1]};
      ev[qq] = __expf((s2.x + s2.y) * SC);
    }
    *(float4*)&es4[k * 4] = make_float4(ev[0], ev[1], ev[2], ev[3]);
  }
  __syncthreads();

  // phase B: thread = (kq = t>>5, c = t&31), 32 k-iters each, packed math.
  int kq = t >> 5, c = t & 31;
  f32x2 den01 = {0.f, 0.f}, den23 = {0.f, 0.f};
  f32x2 num01 = {0.f, 0.f}, num23 = {0.f, 0.f};
  float sumx = 0.f;
  {
    const float* xb = x + (size_t)b * NL * NDIN;
    const unsigned* mbb = mbg + b * NL;
    int k0 = kq * 32;
#pragma unroll 4
    for (int kk = 0; kk < 32; kk++) {
      int k = k0 + kk;
      float4 e4 = *(const float4*)&es4[k * 4];
      float xv = xb[(size_t)k * NDIN + c];
      float mv = ((mbb[k] >> c) & 1u) ? 1.f : 0.f;
      sumx += xv;
      f32x2 e01 = (f32x2){e4.x, e4.y} * mv;   // v_pk_mul
      f32x2 e23 = (f32x2){e4.z, e4.w} * mv;
      den01 += e01;                            // v_pk_add
      den23 += e23;
      num01 += e01 * xv;                       // v_pk_fma
      num23 += e23 * xv;
    }
  }
  float den[4] = {den01.x, den01.y, den23.x, den23.y};
  float num[4] = {num01.x, num01.y, num23.x, num23.y};
  // combine kq pairs within the wave (lane l <-> l+32 differ only in kq)
  sumx += __shfl_xor(sumx, 32, 64);
#pragma unroll
  for (int q = 0; q < 4; q++) {
    den[q] += __shfl_xor(den[q], 32, 64);
    num[q] += __shfl_xor(num[q], 32, 64);
  }
  // waves 1..3 publish partials (stride 9 -> conflict-free)
  {
    int w = t >> 6, lane = t & 63;
    if (w > 0 && lane < 32) {
      float* p = &part[((w - 1) * 32 + c) * 9];
#pragma unroll
      for (int q = 0; q < 4; q++) { p[q] = den[q]; p[4 + q] = num[q]; }
      p[8] = sumx;
    }
  }
  __syncthreads();

  // wave 0 lanes 0-31 combine + finalize
  if (t < 32) {
#pragma unroll
    for (int ww = 0; ww < 3; ww++) {
      const float* p = &part[(ww * 32 + t) * 9];
#pragma unroll
      for (int q = 0; q < 4; q++) { den[q] += p[q]; num[q] += p[4 + q]; }
      sumx += p[8];
    }
    float meanx = sumx * (1.f / 256.f);
#pragma unroll
    for (int qq = 0; qq < 4; qq++) {
      bool any = (den[qq] > 0.f);
      float* ao =
          att + (size_t)(((b * NLQ + qg * 4 + qq) * NH) + h) * 64;
      ao[t]      = any ? (num[qq] / den[qq]) : meanx;
      ao[32 + t] = any ? 1.f : 0.f;
    }
  }
}

// ---------------------------------------------------------------------------
// Kernel 3: out = att @ Wo + bo; XW = out @ W_ih + b_ih + b_hh.
// grid = B*LQ = 1024 blocks, 128 threads. Packed f32x2 FMA, bit-identical
// summation tree to the scalar version ((a0+a1)+(a2+a3)).
// ---------------------------------------------------------------------------
__global__ __launch_bounds__(128) void k_out_xw(
    const float* __restrict__ att,
    const float* __restrict__ Wo, const float* __restrict__ bo,
    const float* __restrict__ Wih, const float* __restrict__ bih,
    const float* __restrict__ bhh, float* __restrict__ XW) {
  int r = blockIdx.x;
  int j = threadIdx.x;
  __shared__ __align__(16) float arow[NH * 64];
  __shared__ __align__(16) float orow[NET];
  arow[j]       = att[(size_t)r * 256 + j];
  arow[j + 128] = att[(size_t)r * 256 + 128 + j];
  __syncthreads();
  f32x2 A = {bo[j], 0.f}, B = {0.f, 0.f};
#pragma unroll 4
  for (int u = 0; u < 256; u += 4) {
    float4 av = *(const float4*)&arow[u];
    A += (f32x2){av.x, av.y} *
         (f32x2){Wo[(size_t)u * NET + j], Wo[(size_t)(u + 1) * NET + j]};
    B += (f32x2){av.z, av.w} *
         (f32x2){Wo[(size_t)(u + 2) * NET + j], Wo[(size_t)(u + 3) * NET + j]};
  }
  orow[j] = (A.x + A.y) + (B.x + B.y);
  __syncthreads();
  f32x2 C = {bih[j] + bhh[j], 0.f}, D = {0.f, 0.f};
#pragma unroll 4
  for (int e = 0; e < NET; e += 4) {
    float4 ov = *(const float4*)&orow[e];
    C += (f32x2){ov.x, ov.y} *
         (f32x2){Wih[(size_t)e * NET + j], Wih[(size_t)(e + 1) * NET + j]};
    D += (f32x2){ov.z, ov.w} *
         (f32x2){Wih[(size_t)(e + 2) * NET + j], Wih[(size_t)(e + 3) * NET + j]};
  }
  XW[(size_t)r * NET + j] = (C.x + C.y) + (D.x + D.y);
}

// ---------------------------------------------------------------------------
// helper: dst[PAD(j)] = b[j] + sum_i src[i] * W[i*128+j], split-2 over s.
// (regressor tail; executed by the first 256 threads of k_rnn)
// ---------------------------------------------------------------------------
__device__ __forceinline__ void layer128(const float* src_lds,
                                         const float* __restrict__ W,
                                         const float* __restrict__ bvec,
                                         float* dst_lds, int j, int s) {
  const float4* h4 = (const float4*)(src_lds + s * 68);
  float a0 = 0.f, a1 = 0.f, a2 = 0.f, a3 = 0.f;
#pragma unroll
  for (int i = 0; i < 16; i++) {
    float4 hv = h4[i];
    int base = (s * 64 + 4 * i) * NET + j;
    a0 += hv.x * W[base];
    a1 += hv.y * W[base + NET];
    a2 += hv.z * W[base + 2 * NET];
    a3 += hv.w * W[base + 3 * NET];
  }
  float acc = (a0 + a1) + (a2 + a3);
  acc += __shfl_xor(acc, 1, 64);
  if (s == 0) dst_lds[PAD(j)] = acc + bvec[j];
}

// ---------------------------------------------------------------------------
// Kernel 4: sequential RNN (64 steps) + regressor. grid = 16, 512 threads.
// thread = (j = tid>>2, s = tid&3): 4-way split, 32-elem dots = 16 pk-FMA,
// 16 f32x2 weights per thread (register-resident). Quarter LDS offsets in
// the PAD layout: {0,32,68,100} floats - 16B aligned, 2-way aliasing only
// (free). Reduction: shfl_xor 1 then 2. Regressor tail: first 256 threads
// in the verified 2-way layout.
// ---------------------------------------------------------------------------
__global__ __launch_bounds__(512, 1) void k_rnn(
    const float* __restrict__ XW, const float* __restrict__ Whh,
    const float* __restrict__ r1w, const float* __restrict__ r1b,
    const float* __restrict__ r2w, const float* __restrict__ r2b,
    const float* __restrict__ r3w, const float* __restrict__ r3b,
    const float* __restrict__ r4w, const float* __restrict__ r4b,
    float* __restrict__ out) {
  int b = blockIdx.x;
  int tid = threadIdx.x;
  int s = tid & 3;
  int j = tid >> 2;
  __shared__ float xwl[NLQ * NET];  // 32 KB, staged once
  __shared__ float hb[2][HPAD];
  __shared__ float tmp[HPAD];
  {
    const float4* src = (const float4*)(XW + (size_t)b * NLQ * NET);
    float4* dst = (float4*)xwl;
#pragma unroll
    for (int u = 0; u < 4; u++) dst[tid + 512 * u] = src[tid + 512 * u];
  }
  // quarter-column weights: 16 f32x2 = 32 VGPR per thread
  int qoff = s * 32;
  f32x2 w2[16];
#pragma unroll
  for (int i = 0; i < 16; i++) {
    w2[i].x = Whh[(size_t)(qoff + 2 * i) * NET + j];
    w2[i].y = Whh[(size_t)(qoff + 2 * i + 1) * NET + j];
  }
  if (tid < 128) hb[0][PAD(tid)] = 0.f;
  __syncthreads();
  int loff = qoff + 4 * (s >> 1);  // padded float offset of quarter s
  for (int t = 0; t < NLQ; t++) {
    float xwv = xwl[t * NET + j];
    const float4* h4 = (const float4*)&hb[t & 1][loff];
    f32x2 accA = {0.f, 0.f}, accB = {0.f, 0.f};
#pragma unroll
    for (int i = 0; i < 8; i++) {
      float4 hv = h4[i];
      accA += (f32x2){hv.x, hv.y} * w2[2 * i];      // v_pk_fma_f32
      accB += (f32x2){hv.z, hv.w} * w2[2 * i + 1];
    }
    float acc = (accA.x + accA.y) + (accB.x + accB.y);
    acc += __shfl_xor(acc, 1, 64);
    acc += __shfl_xor(acc, 2, 64);
    if (s == 0) {
      float z = acc + xwv;
      float e2 = __expf(2.f * z);
      hb[(t + 1) & 1][PAD(j)] = 1.f - 2.f / (e2 + 1.f);  // tanh(z)
    }
    __syncthreads();
  }
  // final h is in hb[0]; regressor on first 256 threads (2-way layout)
  int s2 = tid & 1, j2 = tid >> 1;
  if (tid < 256) layer128(hb[0], r1w, r1b, tmp, j2, s2);
  __syncthreads();
  if (tid < 256) layer128(tmp, r2w, r2b, hb[1], j2, s2);
  __syncthreads();
  if (tid < 256) layer128(hb[1], r3w, r3b, hb[0], j2, s2);
  __syncthreads();
  if (tid < 64) {
    int jj = tid >> 3, p = tid & 7;
    float y = 0.f;
#pragma unroll
    for (int i = 0; i < 16; i++) {
      int ii = p * 16 + i;
      y += hb[0][PAD(ii)] * r4w[ii * 8 + jj];
    }
    y += __shfl_xor(y, 1, 64);
    y += __shfl_xor(y, 2, 64);
    y += __shfl_xor(y, 4, 64);
    if (p == 0) out[b * 8 + jj] = y + r4b[jj];
  }
}

// ---------------------------------------------------------------------------
extern "C" void kernel_launch(void* const* d_in, const int* in_sizes, int n_in,
                              void* d_out, int out_size, void* d_ws, size_t ws_size,
                              hipStream_t stream) {
  const float* x     = (const float*)d_in[0];
  const float* ts    = (const float*)d_in[1];
  const float* mask  = (const float*)d_in[2];
  const float* query = (const float*)d_in[3];
  const float* w_lin = (const float*)d_in[4];
  const float* b_lin = (const float*)d_in[5];
  const float* w_per = (const float*)d_in[6];
  const float* b_per = (const float*)d_in[7];
  const float* Wq    = (const float*)d_in[8];
  const float* bq    = (const float*)d_in[9];
  const float* Wk    = (const float*)d_in[10];
  const float* bk    = (const float*)d_in[11];
  const float* Wo    = (const float*)d_in[12];
  const float* bo    = (const float*)d_in[13];
  const float* Wih   = (const float*)d_in[14];
  const float* bih   = (const float*)d_in[15];
  const float* Whh   = (const float*)d_in[16];
  const float* bhh   = (const float*)d_in[17];
  const float* r1w   = (const float*)d_in[18];
  const float* r1b   = (const float*)d_in[19];
  const float* r2w   = (const float*)d_in[20];
  const float* r2b   = (const float*)d_in[21];
  const float* r3w   = (const float*)d_in[22];
  const float* r3b   = (const float*)d_in[23];
  const float* r4w   = (const float*)d_in[24];
  const float* r4b   = (const float*)d_in[25];
  float* out = (float*)d_out;

  float* ws    = (float*)d_ws;
  float* kproj = ws;                         // 524288 f
  float* qproj = ws + 524288;                // 8192 f
  float* att   = ws + 532480;                // 262144 f
  float* XW    = ws + 794624;                // 131072 f
  unsigned* mbg = (unsigned*)(ws + 925696);  // 4096 u32

  k_embed_proj<<<536, 128, 0, stream>>>(
      ts, query, mask, w_lin, b_lin, w_per, b_per, Wk, bk, Wq, bq,
      kproj, qproj, mbg);
  k_attn<<<NB * NH * 16, 256, 0, stream>>>(x, mbg, qproj, kproj, att);
  k_out_xw<<<NB * NLQ, 128, 0, stream>>>(att, Wo, bo, Wih, bih, bhh, XW);
  k_rnn<<<NB, 512, 0, stream>>>(XW, Whh, r1w, r1b, r2w, r2b, r3w, r3b,
                                r4w, r4b, out);
}